// Round 5
// baseline (904.556 us; speedup 1.0000x reference)
//
#include <hip/hip_runtime.h>
#include <hip/hip_bf16.h>

// GCNConv: out = D^-1/2 (A+I) D^-1/2 (X W) + b
// N=100000, E=1600000, IN=128, OUT=64. edge_index int32, [row(E) | col(E)].
//
// Pipeline v3 — deterministic radix partition + LDS-accumulator aggregate:
//   A1. per-block LDS histogram over 782 node-buckets -> blkcnt[bucket][block]
//   S.  exclusive scan (bucket-major) -> blkoff; bucket_start[b]=blkoff[b][0]
//   A2. place: pairs[pos] = row | lcol<<17, pos from LDS cursors (no global atomics)
//   D.  per-bucket degree count from pairs -> dinv
//   G.  GEMM: hp = (x @ W) * dinv[row]
//   AG. per-bucket aggregate: LDS acc[128][64] += hp[row]; out = dinv*(acc+self)+b

#define IN_CH 128
#define OUT_CH 64
#define BSHIFT 7            // 128 nodes per bucket
#define BNODES 128
#define MAX_NB 800
#define CH_EDGES 16384      // edges per partition block

// ---------------- A1: per-block bucket histogram ----------------
__global__ __launch_bounds__(256) void count_kernel(const int* __restrict__ col,
                                                    int* __restrict__ blkcnt,
                                                    int E, int NBLK, int NB) {
    __shared__ int h[MAX_NB];
    int tid = threadIdx.x;
    for (int i = tid; i < NB; i += 256) h[i] = 0;
    __syncthreads();
    int e0 = blockIdx.x * CH_EDGES;
    #pragma unroll 4
    for (int r = 0; r < CH_EDGES / 256; ++r) {
        int e = e0 + r * 256 + tid;
        if (e < E) atomicAdd(&h[col[e] >> BSHIFT], 1);
    }
    __syncthreads();
    for (int i = tid; i < NB; i += 256) blkcnt[i * NBLK + blockIdx.x] = h[i];
}

// ---------------- two-level exclusive scan over blkcnt ----------------
__global__ __launch_bounds__(256) void scan1_kernel(const int* __restrict__ v_in,
                                                    int* __restrict__ partial, int n) {
    __shared__ int s[256];
    int tid = threadIdx.x;
    int i   = blockIdx.x * 256 + tid;
    int v   = (i < n) ? v_in[i] : 0;
    s[tid] = v; __syncthreads();
    #pragma unroll
    for (int off = 1; off < 256; off <<= 1) {
        int t = (tid >= off) ? s[tid - off] : 0;
        __syncthreads();
        s[tid] += t;
        __syncthreads();
    }
    if (tid == 255) partial[blockIdx.x] = s[255];
}

__global__ __launch_bounds__(512) void scan2_kernel(int* __restrict__ partial, int nb) {
    __shared__ int s[512];
    int tid = threadIdx.x;
    int v   = (tid < nb) ? partial[tid] : 0;
    s[tid] = v; __syncthreads();
    #pragma unroll
    for (int off = 1; off < 512; off <<= 1) {
        int t = (tid >= off) ? s[tid - off] : 0;
        __syncthreads();
        s[tid] += t;
        __syncthreads();
    }
    if (tid < nb) partial[tid] = s[tid] - v;   // exclusive
}

__global__ __launch_bounds__(256) void scan3_kernel(const int* __restrict__ v_in,
                                                    const int* __restrict__ partial,
                                                    int* __restrict__ v_out, int n) {
    __shared__ int s[256];
    int tid = threadIdx.x;
    int i   = blockIdx.x * 256 + tid;
    int v   = (i < n) ? v_in[i] : 0;
    s[tid] = v; __syncthreads();
    #pragma unroll
    for (int off = 1; off < 256; off <<= 1) {
        int t = (tid >= off) ? s[tid - off] : 0;
        __syncthreads();
        s[tid] += t;
        __syncthreads();
    }
    if (i < n) v_out[i] = partial[blockIdx.x] + s[tid] - v;  // exclusive
}

__global__ __launch_bounds__(256) void bstart_kernel(const int* __restrict__ blkoff,
                                                     int* __restrict__ bucket_start,
                                                     int NB, int NBLK, int E) {
    int i = blockIdx.x * 256 + threadIdx.x;
    if (i < NB)  bucket_start[i]  = blkoff[i * NBLK];
    if (i == NB) bucket_start[NB] = E;
}

// ---------------- A2: place into pairs (no global atomics) ----------------
__global__ __launch_bounds__(256) void place_kernel(const int* __restrict__ row,
                                                    const int* __restrict__ col,
                                                    const int* __restrict__ blkoff,
                                                    int* __restrict__ pairs,
                                                    int E, int NBLK, int NB) {
    __shared__ int cur[MAX_NB];
    int tid = threadIdx.x;
    for (int i = tid; i < NB; i += 256) cur[i] = blkoff[i * NBLK + blockIdx.x];
    __syncthreads();
    int e0 = blockIdx.x * CH_EDGES;
    #pragma unroll 4
    for (int r2 = 0; r2 < CH_EDGES / 256; ++r2) {
        int e = e0 + r2 * 256 + tid;
        if (e < E) {
            int c = col[e];
            int b = c >> BSHIFT;
            int pos = atomicAdd(&cur[b], 1);          // LDS atomic
            pairs[pos] = row[e] | ((c & (BNODES - 1)) << 17);   // n < 2^17
        }
    }
}

// ---------------- D: per-bucket degree -> dinv ----------------
__global__ __launch_bounds__(256) void bdeg_kernel(const int* __restrict__ bucket_start,
                                                   const int* __restrict__ pairs,
                                                   float* __restrict__ dinv, int n) {
    __shared__ int cnt[BNODES];
    int tid = threadIdx.x, b = blockIdx.x;
    int node0 = b << BSHIFT;
    if (tid < BNODES) cnt[tid] = 0;
    __syncthreads();
    int s0 = bucket_start[b], s1 = bucket_start[b + 1];
    for (int e = s0 + tid; e < s1; e += 256) atomicAdd(&cnt[pairs[e] >> 17], 1);
    __syncthreads();
    int node = node0 + tid;
    if (tid < BNODES && node < n) dinv[node] = rsqrtf((float)(cnt[tid] + 1));
}

// ---------------- G: GEMM hp = (x @ W) * dinv[row] ----------------
__device__ __forceinline__ void fma4(float4& a, float s, const float4& v) {
    a.x = fmaf(s, v.x, a.x);
    a.y = fmaf(s, v.y, a.y);
    a.z = fmaf(s, v.z, a.z);
    a.w = fmaf(s, v.w, a.w);
}

__global__ __launch_bounds__(256) void gemm_kernel(
    const float* __restrict__ x, const float* __restrict__ W,
    const float* __restrict__ dinv, float* __restrict__ hp, int n)
{
    __shared__ float xl[64 * 128];   // 32 KB, XOR-swizzled float4 chunks
    __shared__ float wl[128 * 64];   // 32 KB, linear k*64+c

    int tid  = threadIdx.x;
    int row0 = blockIdx.x * 64;

    {
        const float4* wg = (const float4*)W;
        float4* wls = (float4*)wl;
        #pragma unroll
        for (int i = 0; i < 8; ++i) wls[tid + i * 256] = wg[tid + i * 256];
    }
    {
        float4* xls = (float4*)xl;
        #pragma unroll
        for (int i = 0; i < 8; ++i) {
            int f  = tid + i * 256;
            int r  = f >> 5;
            int c0 = f & 31;
            int gr = row0 + r;
            float4 v = make_float4(0.f, 0.f, 0.f, 0.f);
            if (gr < n) v = ((const float4*)(x + (size_t)gr * IN_CH))[c0];
            xls[(r << 5) | (c0 ^ (r & 7))] = v;
        }
    }
    __syncthreads();

    int tr = tid & 15;
    int tc = tid >> 4;

    float4 acc0 = {0,0,0,0}, acc1 = {0,0,0,0}, acc2 = {0,0,0,0}, acc3 = {0,0,0,0};
    const float4* xl4 = (const float4*)xl;
    const float4* wl4 = (const float4*)wl;

    #pragma unroll 4
    for (int k4 = 0; k4 < 32; ++k4) {
        int sc = k4 ^ (tr & 7);
        float4 xa0 = xl4[((tr     ) << 5) | sc];
        float4 xa1 = xl4[((tr + 16) << 5) | sc];
        float4 xa2 = xl4[((tr + 32) << 5) | sc];
        float4 xa3 = xl4[((tr + 48) << 5) | sc];
        float4 wb0 = wl4[((k4 * 4 + 0) << 4) | tc];
        float4 wb1 = wl4[((k4 * 4 + 1) << 4) | tc];
        float4 wb2 = wl4[((k4 * 4 + 2) << 4) | tc];
        float4 wb3 = wl4[((k4 * 4 + 3) << 4) | tc];

        fma4(acc0, xa0.x, wb0); fma4(acc0, xa0.y, wb1); fma4(acc0, xa0.z, wb2); fma4(acc0, xa0.w, wb3);
        fma4(acc1, xa1.x, wb0); fma4(acc1, xa1.y, wb1); fma4(acc1, xa1.z, wb2); fma4(acc1, xa1.w, wb3);
        fma4(acc2, xa2.x, wb0); fma4(acc2, xa2.y, wb1); fma4(acc2, xa2.z, wb2); fma4(acc2, xa2.w, wb3);
        fma4(acc3, xa3.x, wb0); fma4(acc3, xa3.y, wb1); fma4(acc3, xa3.z, wb2); fma4(acc3, xa3.w, wb3);
    }

    float4 accs[4] = {acc0, acc1, acc2, acc3};
    #pragma unroll
    for (int i = 0; i < 4; ++i) {
        int gr = row0 + tr + 16 * i;
        if (gr < n) {
            float di = dinv[gr];
            float4 a = accs[i];
            float4 h4 = make_float4(a.x * di, a.y * di, a.z * di, a.w * di);
            ((float4*)(hp + (size_t)gr * OUT_CH))[tc] = h4;
        }
    }
}

// ---------------- AG: per-bucket aggregate via LDS accumulators -------------
__global__ __launch_bounds__(256) void aggregate_kernel(
    const int* __restrict__ bucket_start, const int* __restrict__ pairs,
    const float* __restrict__ hp, const float* __restrict__ dinv,
    const float* __restrict__ bias, float* __restrict__ out, int n)
{
    __shared__ float acc[BNODES * OUT_CH];   // 32 KB
    int tid = threadIdx.x;
    int b = blockIdx.x, node0 = b << BSHIFT;

    float4* a4 = (float4*)acc;
    #pragma unroll
    for (int i = 0; i < 8; ++i) a4[tid + i * 256] = make_float4(0.f, 0.f, 0.f, 0.f);
    __syncthreads();

    int lane = tid & 63, wave = tid >> 6;
    int s0 = bucket_start[b], s1 = bucket_start[b + 1];

    for (int base = s0 + wave * 64; base < s1; base += 256) {
        int cnt = min(64, s1 - base);
        int p   = (base + lane < s1) ? pairs[base + lane] : 0;
        int j = 0;
        for (; j + 4 <= cnt; j += 4) {
            int p0 = __shfl(p, j);
            int p1 = __shfl(p, j + 1);
            int p2 = __shfl(p, j + 2);
            int p3 = __shfl(p, j + 3);
            float v0 = hp[(size_t)(p0 & 0x1FFFF) * OUT_CH + lane];
            float v1 = hp[(size_t)(p1 & 0x1FFFF) * OUT_CH + lane];
            float v2 = hp[(size_t)(p2 & 0x1FFFF) * OUT_CH + lane];
            float v3 = hp[(size_t)(p3 & 0x1FFFF) * OUT_CH + lane];
            atomicAdd(&acc[(p0 >> 17) * OUT_CH + lane], v0);
            atomicAdd(&acc[(p1 >> 17) * OUT_CH + lane], v1);
            atomicAdd(&acc[(p2 >> 17) * OUT_CH + lane], v2);
            atomicAdd(&acc[(p3 >> 17) * OUT_CH + lane], v3);
        }
        for (; j < cnt; ++j) {
            int pj = __shfl(p, j);
            atomicAdd(&acc[(pj >> 17) * OUT_CH + lane],
                      hp[(size_t)(pj & 0x1FFFF) * OUT_CH + lane]);
        }
    }
    __syncthreads();

    int nodeCnt = min(BNODES, n - node0);
    float bl = bias[lane];
    for (int lc = wave; lc < nodeCnt; lc += 4) {
        int node = node0 + lc;
        float d    = dinv[node];
        float self = hp[(size_t)node * OUT_CH + lane];
        out[(size_t)node * OUT_CH + lane] = fmaf(d, acc[lc * OUT_CH + lane] + self, bl);
    }
}

extern "C" void kernel_launch(void* const* d_in, const int* in_sizes, int n_in,
                              void* d_out, int out_size, void* d_ws, size_t ws_size,
                              hipStream_t stream) {
    const float* x  = (const float*)d_in[0];
    const int*   ei = (const int*)d_in[1];
    const float* W  = (const float*)d_in[2];
    const float* b  = (const float*)d_in[3];
    float*       out = (float*)d_out;

    int n = in_sizes[0] / IN_CH;     // 100000
    int E = in_sizes[1] / 2;         // 1600000
    const int* row = ei;
    const int* col = ei + E;

    int NB   = (n + BNODES - 1) >> BSHIFT;           // 782
    int NBLK = (E + CH_EDGES - 1) / CH_EDGES;        // 98
    int TOT  = NB * NBLK;                            // 76636
    int nbs  = (TOT + 255) / 256;                    // 300 (<=512)

    // workspace layout
    char* ws = (char*)d_ws;
    int*   blkcnt       = (int*)ws;   ws += (size_t)TOT * 4;
    int*   blkoff       = (int*)ws;   ws += (size_t)TOT * 4;
    int*   partial      = (int*)ws;   ws += 512 * 4;
    int*   bucket_start = (int*)ws;   ws += (size_t)(NB + 1) * 4;
    float* dinv         = (float*)ws; ws += (size_t)n * 4;
    int*   pairs        = (int*)ws;   ws += (size_t)E * 4;
    ws = (char*)(((uintptr_t)ws + 255) & ~(uintptr_t)255);
    float* hp           = (float*)ws;                // n*64 floats

    count_kernel    <<<NBLK, 256, 0, stream>>>(col, blkcnt, E, NBLK, NB);
    scan1_kernel    <<<nbs, 256, 0, stream>>>(blkcnt, partial, TOT);
    scan2_kernel    <<<1, 512, 0, stream>>>(partial, nbs);
    scan3_kernel    <<<nbs, 256, 0, stream>>>(blkcnt, partial, blkoff, TOT);
    bstart_kernel   <<<(NB + 256) / 256, 256, 0, stream>>>(blkoff, bucket_start, NB, NBLK, E);
    place_kernel    <<<NBLK, 256, 0, stream>>>(row, col, blkoff, pairs, E, NBLK, NB);
    bdeg_kernel     <<<NB, 256, 0, stream>>>(bucket_start, pairs, dinv, n);
    gemm_kernel     <<<(n + 63) / 64, 256, 0, stream>>>(x, W, dinv, hp, n);
    aggregate_kernel<<<NB, 256, 0, stream>>>(bucket_start, pairs, hp, dinv, b, out, n);
}

// Round 6
// 283.121 us; speedup vs baseline: 3.1949x; 3.1949x over previous
//
#include <hip/hip_runtime.h>
#include <hip/hip_bf16.h>

// GCNConv: out = D^-1/2 (A+I) D^-1/2 (X W) + b
// N=100000, E=1600000, IN=128, OUT=64. edge_index int32, [row(E) | col(E)].
//
// Pipeline v4 — deterministic hierarchical counting sort + wave-per-node CSR:
//   A1. count: per-block LDS histogram over 782 buckets -> blkcnt[bucket][block]
//   S1. scan blkcnt -> blkoff (exclusive, bucket-major); bucket_start
//   A2. place: pairs[pos] = row | lcol<<17 (LDS cursors, no global atomics)
//   D.  bdeg: per-bucket node degree from pairs -> deg, dinv
//   S2. scan deg -> row_start
//   F.  bucket_fill: pairs -> csr_row (node-sorted, 8 KB L2 write window)
//   G.  GEMM: hp = (x @ W) * dinv[row]        (hp overlays pairs)
//   AG. aggregate: one wave per node, 8-deep gather unroll

#define IN_CH 128
#define OUT_CH 64
#define BSHIFT 7            // 128 nodes per bucket
#define BNODES 128
#define MAX_NB 800
#define CH_EDGES 16384      // edges per partition block

// ---------------- A1: per-block bucket histogram ----------------
__global__ __launch_bounds__(256) void count_kernel(const int* __restrict__ col,
                                                    int* __restrict__ blkcnt,
                                                    int E, int NBLK, int NB) {
    __shared__ int h[MAX_NB];
    int tid = threadIdx.x;
    for (int i = tid; i < NB; i += 256) h[i] = 0;
    __syncthreads();
    int e0 = blockIdx.x * CH_EDGES;
    #pragma unroll 4
    for (int r = 0; r < CH_EDGES / 256; ++r) {
        int e = e0 + r * 256 + tid;
        if (e < E) atomicAdd(&h[col[e] >> BSHIFT], 1);
    }
    __syncthreads();
    for (int i = tid; i < NB; i += 256) blkcnt[i * NBLK + blockIdx.x] = h[i];
}

// ---------------- generic two-level exclusive scan ----------------
__global__ __launch_bounds__(256) void scan1_kernel(const int* __restrict__ v_in,
                                                    int* __restrict__ partial, int n) {
    __shared__ int s[256];
    int tid = threadIdx.x;
    int i   = blockIdx.x * 256 + tid;
    int v   = (i < n) ? v_in[i] : 0;
    s[tid] = v; __syncthreads();
    #pragma unroll
    for (int off = 1; off < 256; off <<= 1) {
        int t = (tid >= off) ? s[tid - off] : 0;
        __syncthreads();
        s[tid] += t;
        __syncthreads();
    }
    if (tid == 255) partial[blockIdx.x] = s[255];
}

__global__ __launch_bounds__(512) void scan2_kernel(int* __restrict__ partial, int nb) {
    __shared__ int s[512];
    int tid = threadIdx.x;
    int v   = (tid < nb) ? partial[tid] : 0;
    s[tid] = v; __syncthreads();
    #pragma unroll
    for (int off = 1; off < 512; off <<= 1) {
        int t = (tid >= off) ? s[tid - off] : 0;
        __syncthreads();
        s[tid] += t;
        __syncthreads();
    }
    if (tid < nb) partial[tid] = s[tid] - v;   // exclusive
}

// writes v_out[i] = exclusive prefix; if i==n_tail writes E_tail
__global__ __launch_bounds__(256) void scan3_kernel(const int* __restrict__ v_in,
                                                    const int* __restrict__ partial,
                                                    int* __restrict__ v_out,
                                                    int n, int n_tail, int E_tail) {
    __shared__ int s[256];
    int tid = threadIdx.x;
    int i   = blockIdx.x * 256 + tid;
    int v   = (i < n) ? v_in[i] : 0;
    s[tid] = v; __syncthreads();
    #pragma unroll
    for (int off = 1; off < 256; off <<= 1) {
        int t = (tid >= off) ? s[tid - off] : 0;
        __syncthreads();
        s[tid] += t;
        __syncthreads();
    }
    if (i < n) v_out[i] = partial[blockIdx.x] + s[tid] - v;  // exclusive
    if (n_tail >= 0 && i == 0 && blockIdx.x == 0) v_out[n_tail] = E_tail;
}

__global__ __launch_bounds__(256) void bstart_kernel(const int* __restrict__ blkoff,
                                                     int* __restrict__ bucket_start,
                                                     int NB, int NBLK, int E) {
    int i = blockIdx.x * 256 + threadIdx.x;
    if (i < NB)  bucket_start[i]  = blkoff[i * NBLK];
    if (i == NB) bucket_start[NB] = E;
}

// ---------------- A2: place into pairs (no global atomics) ----------------
__global__ __launch_bounds__(256) void place_kernel(const int* __restrict__ row,
                                                    const int* __restrict__ col,
                                                    const int* __restrict__ blkoff,
                                                    int* __restrict__ pairs,
                                                    int E, int NBLK, int NB) {
    __shared__ int cur[MAX_NB];
    int tid = threadIdx.x;
    for (int i = tid; i < NB; i += 256) cur[i] = blkoff[i * NBLK + blockIdx.x];
    __syncthreads();
    int e0 = blockIdx.x * CH_EDGES;
    #pragma unroll 4
    for (int r2 = 0; r2 < CH_EDGES / 256; ++r2) {
        int e = e0 + r2 * 256 + tid;
        if (e < E) {
            int c = col[e];
            int b = c >> BSHIFT;
            int pos = atomicAdd(&cur[b], 1);          // LDS atomic
            pairs[pos] = row[e] | ((c & (BNODES - 1)) << 17);   // n < 2^17
        }
    }
}

// ---------------- D: per-bucket degree -> deg, dinv ----------------
__global__ __launch_bounds__(256) void bdeg_kernel(const int* __restrict__ bucket_start,
                                                   const int* __restrict__ pairs,
                                                   int* __restrict__ deg,
                                                   float* __restrict__ dinv, int n) {
    __shared__ int cnt[BNODES];
    int tid = threadIdx.x, b = blockIdx.x;
    int node0 = b << BSHIFT;
    if (tid < BNODES) cnt[tid] = 0;
    __syncthreads();
    int s0 = bucket_start[b], s1 = bucket_start[b + 1];
    for (int e = s0 + tid; e < s1; e += 256) atomicAdd(&cnt[pairs[e] >> 17], 1);
    __syncthreads();
    int node = node0 + tid;
    if (tid < BNODES && node < n) {
        deg[node]  = cnt[tid];
        dinv[node] = rsqrtf((float)(cnt[tid] + 1));   // +1 self loop
    }
}

// ---------------- F: bucket_fill pairs -> csr_row (node-sorted) -------------
__global__ __launch_bounds__(256) void bucket_fill_kernel(const int* __restrict__ bucket_start,
                                                          const int* __restrict__ row_start,
                                                          const int* __restrict__ pairs,
                                                          int* __restrict__ csr_row, int n) {
    __shared__ int lcur[BNODES];
    int b     = blockIdx.x;
    int node0 = b << BSHIFT;
    int tid   = threadIdx.x;
    int nodeCnt = min(BNODES, n - node0);
    if (tid < nodeCnt) lcur[tid] = row_start[node0 + tid];
    __syncthreads();
    int s0 = bucket_start[b], s1 = bucket_start[b + 1];
    for (int e = s0 + tid; e < s1; e += 256) {
        int p   = pairs[e];
        int pos = atomicAdd(&lcur[p >> 17], 1);
        csr_row[pos] = p & 0x1FFFF;
    }
}

// ---------------- G: GEMM hp = (x @ W) * dinv[row] ----------------
__device__ __forceinline__ void fma4(float4& a, float s, const float4& v) {
    a.x = fmaf(s, v.x, a.x);
    a.y = fmaf(s, v.y, a.y);
    a.z = fmaf(s, v.z, a.z);
    a.w = fmaf(s, v.w, a.w);
}

__global__ __launch_bounds__(256) void gemm_kernel(
    const float* __restrict__ x, const float* __restrict__ W,
    const float* __restrict__ dinv, float* __restrict__ hp, int n)
{
    __shared__ float xl[64 * 128];   // 32 KB, XOR-swizzled float4 chunks
    __shared__ float wl[128 * 64];   // 32 KB, linear k*64+c

    int tid  = threadIdx.x;
    int row0 = blockIdx.x * 64;

    {
        const float4* wg = (const float4*)W;
        float4* wls = (float4*)wl;
        #pragma unroll
        for (int i = 0; i < 8; ++i) wls[tid + i * 256] = wg[tid + i * 256];
    }
    {
        float4* xls = (float4*)xl;
        #pragma unroll
        for (int i = 0; i < 8; ++i) {
            int f  = tid + i * 256;
            int r  = f >> 5;
            int c0 = f & 31;
            int gr = row0 + r;
            float4 v = make_float4(0.f, 0.f, 0.f, 0.f);
            if (gr < n) v = ((const float4*)(x + (size_t)gr * IN_CH))[c0];
            xls[(r << 5) | (c0 ^ (r & 7))] = v;
        }
    }
    __syncthreads();

    int tr = tid & 15;
    int tc = tid >> 4;

    float4 acc0 = {0,0,0,0}, acc1 = {0,0,0,0}, acc2 = {0,0,0,0}, acc3 = {0,0,0,0};
    const float4* xl4 = (const float4*)xl;
    const float4* wl4 = (const float4*)wl;

    #pragma unroll 4
    for (int k4 = 0; k4 < 32; ++k4) {
        int sc = k4 ^ (tr & 7);
        float4 xa0 = xl4[((tr     ) << 5) | sc];
        float4 xa1 = xl4[((tr + 16) << 5) | sc];
        float4 xa2 = xl4[((tr + 32) << 5) | sc];
        float4 xa3 = xl4[((tr + 48) << 5) | sc];
        float4 wb0 = wl4[((k4 * 4 + 0) << 4) | tc];
        float4 wb1 = wl4[((k4 * 4 + 1) << 4) | tc];
        float4 wb2 = wl4[((k4 * 4 + 2) << 4) | tc];
        float4 wb3 = wl4[((k4 * 4 + 3) << 4) | tc];

        fma4(acc0, xa0.x, wb0); fma4(acc0, xa0.y, wb1); fma4(acc0, xa0.z, wb2); fma4(acc0, xa0.w, wb3);
        fma4(acc1, xa1.x, wb0); fma4(acc1, xa1.y, wb1); fma4(acc1, xa1.z, wb2); fma4(acc1, xa1.w, wb3);
        fma4(acc2, xa2.x, wb0); fma4(acc2, xa2.y, wb1); fma4(acc2, xa2.z, wb2); fma4(acc2, xa2.w, wb3);
        fma4(acc3, xa3.x, wb0); fma4(acc3, xa3.y, wb1); fma4(acc3, xa3.z, wb2); fma4(acc3, xa3.w, wb3);
    }

    float4 accs[4] = {acc0, acc1, acc2, acc3};
    #pragma unroll
    for (int i = 0; i < 4; ++i) {
        int gr = row0 + tr + 16 * i;
        if (gr < n) {
            float di = dinv[gr];
            float4 a = accs[i];
            float4 h4 = make_float4(a.x * di, a.y * di, a.z * di, a.w * di);
            ((float4*)(hp + (size_t)gr * OUT_CH))[tc] = h4;
        }
    }
}

// ---------------- AG: out[c] = dinv[c]*(hp[c] + sum hp[r]) + b --------------
// One wave per node, lane = channel, 8-deep gather unroll for latency hiding.
__global__ __launch_bounds__(256) void aggregate_kernel(
    const int* __restrict__ row_start, const int* __restrict__ csr_row,
    const float* __restrict__ hp, const float* __restrict__ dinv,
    const float* __restrict__ bias, float* __restrict__ out, int n)
{
    int wid  = (blockIdx.x * 256 + threadIdx.x) >> 6;   // node id
    int lane = threadIdx.x & 63;
    if (wid >= n) return;

    int s0 = row_start[wid];
    int s1 = row_start[wid + 1];

    float self = hp[(size_t)wid * OUT_CH + lane];
    float a0 = 0.f, a1 = 0.f, a2 = 0.f, a3 = 0.f;
    float a4 = 0.f, a5 = 0.f, a6 = 0.f, a7 = 0.f;

    for (int base = s0; base < s1; base += 64) {
        int cnt  = min(64, s1 - base);
        int ridx = (base + lane < s1) ? csr_row[base + lane] : 0;
        int j = 0;
        for (; j + 8 <= cnt; j += 8) {
            int r0 = __shfl(ridx, j);
            int r1 = __shfl(ridx, j + 1);
            int r2 = __shfl(ridx, j + 2);
            int r3 = __shfl(ridx, j + 3);
            int r4 = __shfl(ridx, j + 4);
            int r5 = __shfl(ridx, j + 5);
            int r6 = __shfl(ridx, j + 6);
            int r7 = __shfl(ridx, j + 7);
            a0 += hp[(size_t)r0 * OUT_CH + lane];
            a1 += hp[(size_t)r1 * OUT_CH + lane];
            a2 += hp[(size_t)r2 * OUT_CH + lane];
            a3 += hp[(size_t)r3 * OUT_CH + lane];
            a4 += hp[(size_t)r4 * OUT_CH + lane];
            a5 += hp[(size_t)r5 * OUT_CH + lane];
            a6 += hp[(size_t)r6 * OUT_CH + lane];
            a7 += hp[(size_t)r7 * OUT_CH + lane];
        }
        for (; j < cnt; ++j) {
            int r = __shfl(ridx, j);
            a0 += hp[(size_t)r * OUT_CH + lane];
        }
    }
    float acc = self + (((a0 + a1) + (a2 + a3)) + ((a4 + a5) + (a6 + a7)));
    out[(size_t)wid * OUT_CH + lane] = fmaf(dinv[wid], acc, bias[lane]);
}

extern "C" void kernel_launch(void* const* d_in, const int* in_sizes, int n_in,
                              void* d_out, int out_size, void* d_ws, size_t ws_size,
                              hipStream_t stream) {
    const float* x  = (const float*)d_in[0];
    const int*   ei = (const int*)d_in[1];
    const float* W  = (const float*)d_in[2];
    const float* b  = (const float*)d_in[3];
    float*       out = (float*)d_out;

    int n = in_sizes[0] / IN_CH;     // 100000
    int E = in_sizes[1] / 2;         // 1600000
    const int* row = ei;
    const int* col = ei + E;

    int NB   = (n + BNODES - 1) >> BSHIFT;           // 782
    int NBLK = (E + CH_EDGES - 1) / CH_EDGES;        // 98
    int TOT  = NB * NBLK;                            // 76636
    int nbs  = (TOT + 255) / 256;                    // 300 (<=512)
    int nbn  = (n + 255) / 256;                      // 391 (<=512)

    // workspace layout; hp overlays pairs (gemm launches after bucket_fill)
    char* ws = (char*)d_ws;
    int*   blkcnt       = (int*)ws;   ws += (size_t)TOT * 4;
    int*   blkoff       = (int*)ws;   ws += (size_t)TOT * 4;
    int*   partial      = (int*)ws;   ws += 512 * 4;
    int*   bucket_start = (int*)ws;   ws += (size_t)(NB + 1) * 4;
    int*   deg          = (int*)ws;   ws += (size_t)n * 4;
    int*   row_start    = (int*)ws;   ws += (size_t)(n + 1) * 4;
    float* dinv         = (float*)ws; ws += (size_t)n * 4;
    int*   csr_row      = (int*)ws;   ws += (size_t)E * 4;
    ws = (char*)(((uintptr_t)ws + 255) & ~(uintptr_t)255);
    int*   pairs        = (int*)ws;   // E ints      (phase 1)
    float* hp           = (float*)ws; // n*64 floats (phase 2, overlays pairs)

    count_kernel      <<<NBLK, 256, 0, stream>>>(col, blkcnt, E, NBLK, NB);
    scan1_kernel      <<<nbs, 256, 0, stream>>>(blkcnt, partial, TOT);
    scan2_kernel      <<<1, 512, 0, stream>>>(partial, nbs);
    scan3_kernel      <<<nbs, 256, 0, stream>>>(blkcnt, partial, blkoff, TOT, -1, 0);
    bstart_kernel     <<<(NB + 256) / 256, 256, 0, stream>>>(blkoff, bucket_start, NB, NBLK, E);
    place_kernel      <<<NBLK, 256, 0, stream>>>(row, col, blkoff, pairs, E, NBLK, NB);
    bdeg_kernel       <<<NB, 256, 0, stream>>>(bucket_start, pairs, deg, dinv, n);
    scan1_kernel      <<<nbn, 256, 0, stream>>>(deg, partial, n);
    scan2_kernel      <<<1, 512, 0, stream>>>(partial, nbn);
    scan3_kernel      <<<nbn, 256, 0, stream>>>(deg, partial, row_start, n, n, E);
    bucket_fill_kernel<<<NB, 256, 0, stream>>>(bucket_start, row_start, pairs, csr_row, n);
    gemm_kernel       <<<(n + 63) / 64, 256, 0, stream>>>(x, W, dinv, hp, n);
    aggregate_kernel  <<<(n + 3) / 4, 256, 0, stream>>>(row_start, csr_row, hp, dinv, b, out, n);
}